// Round 2
// baseline (1800.361 us; speedup 1.0000x reference)
//
#include <hip/hip_runtime.h>
#include <math.h>

#define DIM 1024
#define NS  65536
#define NC  64
#define SMAX 14

// ---------------------------------------------------------------- buildA
// A = Araw - Araw^T + diag(D), tiled transpose through LDS
__global__ __launch_bounds__(256) void k_buildA(const float* __restrict__ Araw,
                                                const float* __restrict__ Dv,
                                                float* __restrict__ A) {
    __shared__ float tileT[32][33];
    int bx = blockIdx.x & 31, by = blockIdx.x >> 5;  // tile col, tile row
    int i0 = by * 32, j0 = bx * 32;
    int tx = threadIdx.x & 31, ty = threadIdx.x >> 5; // ty in 0..7
    #pragma unroll
    for (int rr = 0; rr < 32; rr += 8)
        tileT[rr + ty][tx] = Araw[(j0 + rr + ty) * DIM + i0 + tx];
    __syncthreads();
    #pragma unroll
    for (int rr = 0; rr < 32; rr += 8) {
        int i = i0 + rr + ty, j = j0 + tx;
        float v = Araw[i * DIM + j] - tileT[tx][rr + ty];
        if (i == j) v += Dv[i];
        A[i * DIM + j] = v;
    }
}

// ---------------------------------------------------------------- 1-norm
__global__ __launch_bounds__(256) void k_colsum(const float* __restrict__ A,
                                                float* __restrict__ colp) {
    int cg = blockIdx.x & 3, rg = blockIdx.x >> 2;   // 4 col groups x 8 row groups
    int j = cg * 256 + threadIdx.x;
    float s = 0.f;
    int ibase = rg * 128;
    for (int i = 0; i < 128; ++i) s += fabsf(A[(ibase + i) * DIM + j]);
    colp[rg * 1024 + j] = s;
}

__global__ __launch_bounds__(1024) void k_snorm(const float* __restrict__ colp,
                                                int* __restrict__ sInt) {
    __shared__ float red[1024];
    int t = threadIdx.x;
    float s = 0.f;
    #pragma unroll
    for (int sl = 0; sl < 8; ++sl) s += colp[sl * 1024 + t];
    red[t] = s;
    __syncthreads();
    for (int w = 512; w >= 1; w >>= 1) {
        if (t < w) red[t] = fmaxf(red[t], red[t + w]);
        __syncthreads();
    }
    if (t == 0) {
        float n1 = red[0];
        int sv = 0;
        if (n1 > 0.25f) sv = (int)ceilf(log2f(n1 * 4.0f)); // theta <= 0.25
        if (sv < 0) sv = 0;
        if (sv > SMAX) sv = SMAX;
        sInt[0] = sv;
    }
}

// ---------------------------------------------------------------- scale / init
__global__ __launch_bounds__(256) void k_scaleM(const float* __restrict__ A,
                                                float* __restrict__ M,
                                                const int* __restrict__ sInt) {
    float sc = ldexpf(1.0f, -sInt[0]);
    int idx = (blockIdx.x * 256 + threadIdx.x) << 2;
    float4 v = *(const float4*)(A + idx);
    v.x *= sc; v.y *= sc; v.z *= sc; v.w *= sc;
    *(float4*)(M + idx) = v;
}

// T = alpha*M + I
__global__ __launch_bounds__(256) void k_axpyI(const float* __restrict__ M,
                                               float* __restrict__ T, float alpha) {
    int idx = (blockIdx.x * 256 + threadIdx.x) << 2;
    int row = idx >> 10, d = row - (idx & 1023);
    float4 v = *(const float4*)(M + idx);
    v.x *= alpha; v.y *= alpha; v.z *= alpha; v.w *= alpha;
    if (d >= 0 && d < 4) ((float*)&v)[d] += 1.0f;
    *(float4*)(T + idx) = v;
}

// ---------------------------------------------------------------- GEMM 1024^3, split-K=2
#define GTS 64
#define GBK 16

#define FMA16(a, b)                                                                               \
    acc[0][0] = fmaf(a.x, b.x, acc[0][0]); acc[0][1] = fmaf(a.x, b.y, acc[0][1]);                 \
    acc[0][2] = fmaf(a.x, b.z, acc[0][2]); acc[0][3] = fmaf(a.x, b.w, acc[0][3]);                 \
    acc[1][0] = fmaf(a.y, b.x, acc[1][0]); acc[1][1] = fmaf(a.y, b.y, acc[1][1]);                 \
    acc[1][2] = fmaf(a.y, b.z, acc[1][2]); acc[1][3] = fmaf(a.y, b.w, acc[1][3]);                 \
    acc[2][0] = fmaf(a.z, b.x, acc[2][0]); acc[2][1] = fmaf(a.z, b.y, acc[2][1]);                 \
    acc[2][2] = fmaf(a.z, b.z, acc[2][2]); acc[2][3] = fmaf(a.z, b.w, acc[2][3]);                 \
    acc[3][0] = fmaf(a.w, b.x, acc[3][0]); acc[3][1] = fmaf(a.w, b.y, acc[3][1]);                 \
    acc[3][2] = fmaf(a.w, b.z, acc[3][2]); acc[3][3] = fmaf(a.w, b.w, acc[3][3]);

// partial[slice] = A[:, k-slice] * B[k-slice, :]; skipped when step >= s (copy mode)
__global__ __launch_bounds__(256) void k_gemm_part(const float* __restrict__ A,
                                                   const float* __restrict__ B,
                                                   float* __restrict__ part,
                                                   int step, const int* __restrict__ sInt) {
    if (step >= 0 && step >= sInt[0]) return;
    __shared__ float As[GBK][GTS], Bs[GBK][GTS];
    int bid = blockIdx.x;
    int slice = bid >> 8, tile = bid & 255;
    int m0 = (tile >> 4) * GTS, n0 = (tile & 15) * GTS;
    int k0 = slice * 512;
    int tid = threadIdx.x;
    int ar = tid >> 2, ak = (tid & 3) << 2;   // A tile: 64 rows x 16 k
    int bk = tid >> 4, bc = (tid & 15) << 2;  // B tile: 16 k x 64 cols
    const float* Ap = A + (m0 + ar) * DIM + k0 + ak;
    const float* Bp = B + (k0 + bk) * DIM + n0 + bc;
    float4 av = *(const float4*)Ap;
    float4 bv = *(const float4*)Bp;
    float acc[4][4] = {};
    int ty = tid >> 4, tx = tid & 15;
    for (int kt = GBK; kt <= 512; kt += GBK) {
        As[ak + 0][ar] = av.x; As[ak + 1][ar] = av.y;
        As[ak + 2][ar] = av.z; As[ak + 3][ar] = av.w;
        *(float4*)&Bs[bk][bc] = bv;
        __syncthreads();
        if (kt < 512) {
            av = *(const float4*)(Ap + kt);
            bv = *(const float4*)(Bp + kt * DIM);
        }
        #pragma unroll
        for (int k = 0; k < GBK; ++k) {
            const float4 a = *(const float4*)&As[k][ty << 2];
            const float4 b = *(const float4*)&Bs[k][tx << 2];
            FMA16(a, b)
        }
        __syncthreads();
    }
    float* C = part + slice * DIM * DIM + (m0 + (ty << 2)) * DIM + n0 + (tx << 2);
    #pragma unroll
    for (int i = 0; i < 4; ++i)
        *(float4*)(C + i * DIM) = make_float4(acc[i][0], acc[i][1], acc[i][2], acc[i][3]);
}

// C = alpha*(p0+p1) + addI*I   (or C = src when step >= s)
__global__ __launch_bounds__(256) void k_combine(const float* __restrict__ part,
                                                 const float* __restrict__ src,
                                                 float* __restrict__ C,
                                                 float alpha, int addI,
                                                 int step, const int* __restrict__ sInt) {
    int idx = (blockIdx.x * 256 + threadIdx.x) << 2;
    float4 o;
    if (step >= 0 && step >= sInt[0]) {
        o = *(const float4*)(src + idx);
    } else {
        float4 p0 = *(const float4*)(part + idx);
        float4 p1 = *(const float4*)(part + DIM * DIM + idx);
        o.x = alpha * (p0.x + p1.x);
        o.y = alpha * (p0.y + p1.y);
        o.z = alpha * (p0.z + p1.z);
        o.w = alpha * (p0.w + p1.w);
        if (addI) {
            int row = idx >> 10, d = row - (idx & 1023);
            if (d >= 0 && d < 4) ((float*)&o)[d] += 1.0f;
        }
    }
    *(float4*)(C + idx) = o;
}

// ---------------------------------------------------------------- L = sigmoid(L_raw)
__global__ __launch_bounds__(256) void k_sigmoid(const float* __restrict__ Lraw,
                                                 float* __restrict__ Lsig) {
    int i = blockIdx.x * 256 + threadIdx.x;
    float v = Lraw[i];
    Lsig[i] = 1.0f / (1.0f + expf(-v));
}

// ---------------------------------------------------------------- PL = P @ Lsig (split-K=8)
__global__ __launch_bounds__(256) void k_pl_part(const float* __restrict__ P,
                                                 const float* __restrict__ L,
                                                 float* __restrict__ plp) {
    __shared__ float As[16][64], Bs[16][64];
    int slice = blockIdx.x >> 4, mt = blockIdx.x & 15;
    int m0 = mt << 6, k0 = slice << 7;
    int tid = threadIdx.x;
    int ar = tid >> 2, ak = (tid & 3) << 2;
    int bk = tid >> 4, bc = (tid & 15) << 2;
    int ty = tid >> 4, tx = tid & 15;
    float acc[4][4] = {};
    for (int kt = 0; kt < 128; kt += 16) {
        float4 av = *(const float4*)(P + (m0 + ar) * DIM + k0 + kt + ak);
        float4 bv = *(const float4*)(L + (k0 + kt + bk) * NC + bc);
        __syncthreads();
        As[ak + 0][ar] = av.x; As[ak + 1][ar] = av.y;
        As[ak + 2][ar] = av.z; As[ak + 3][ar] = av.w;
        *(float4*)&Bs[bk][bc] = bv;
        __syncthreads();
        #pragma unroll
        for (int k = 0; k < 16; ++k) {
            const float4 a = *(const float4*)&As[k][ty << 2];
            const float4 b = *(const float4*)&Bs[k][tx << 2];
            FMA16(a, b)
        }
    }
    float* C = plp + slice * DIM * NC + (m0 + (ty << 2)) * NC + (tx << 2);
    #pragma unroll
    for (int i = 0; i < 4; ++i)
        *(float4*)(C + i * NC) = make_float4(acc[i][0], acc[i][1], acc[i][2], acc[i][3]);
}

__global__ __launch_bounds__(256) void k_pl_comb(const float* __restrict__ plp,
                                                 float* __restrict__ PL) {
    int idx = (blockIdx.x * 256 + threadIdx.x) << 2;
    float4 s = *(const float4*)(plp + idx);
    #pragma unroll
    for (int sl = 1; sl < 8; ++sl) {
        const float4 v = *(const float4*)(plp + sl * DIM * NC + idx);
        s.x += v.x; s.y += v.y; s.z += v.z; s.w += v.w;
    }
    *(float4*)(PL + idx) = s;
}

// ---------------------------------------------------------------- proj = X @ PL (writes prob & proj)
#define PBM 128
#define PBK 32
__global__ __launch_bounds__(256) void k_proj(const float* __restrict__ X,
                                              const float* __restrict__ PL,
                                              float* __restrict__ outProb,
                                              float* __restrict__ outProj) {
    __shared__ float Xs[PBK][PBM], Ps[PBK][NC];
    int m0 = blockIdx.x * PBM;
    int tid = threadIdx.x;
    int xr = tid >> 3, xk = (tid & 7) << 2;   // 32 rows x 32 k per load pass, x4 passes
    int pk = tid >> 4, pc = (tid & 15) << 2;  // 16 k x 64 cols per pass, x2
    const float* Xp = X + (m0 + xr) * DIM + xk;
    float4 xv[4], pv[2];
    #pragma unroll
    for (int i = 0; i < 4; ++i) xv[i] = *(const float4*)(Xp + i * 32 * DIM);
    #pragma unroll
    for (int i = 0; i < 2; ++i) pv[i] = *(const float4*)(PL + (pk + i * 16) * NC + pc);
    float acc[8][4] = {};
    int ty = tid >> 4, tx = tid & 15;
    for (int kt = PBK; kt <= DIM; kt += PBK) {
        #pragma unroll
        for (int i = 0; i < 4; ++i) {
            Xs[xk + 0][xr + i * 32] = xv[i].x;
            Xs[xk + 1][xr + i * 32] = xv[i].y;
            Xs[xk + 2][xr + i * 32] = xv[i].z;
            Xs[xk + 3][xr + i * 32] = xv[i].w;
        }
        #pragma unroll
        for (int i = 0; i < 2; ++i) *(float4*)&Ps[pk + i * 16][pc] = pv[i];
        __syncthreads();
        if (kt < DIM) {
            #pragma unroll
            for (int i = 0; i < 4; ++i) xv[i] = *(const float4*)(Xp + kt + i * 32 * DIM);
            #pragma unroll
            for (int i = 0; i < 2; ++i)
                pv[i] = *(const float4*)(PL + (kt + pk + i * 16) * NC + pc);
        }
        #pragma unroll
        for (int k = 0; k < PBK; ++k) {
            const float4 a0 = *(const float4*)&Xs[k][ty << 3];
            const float4 a1 = *(const float4*)&Xs[k][(ty << 3) + 4];
            const float4 b  = *(const float4*)&Ps[k][tx << 2];
            acc[0][0]=fmaf(a0.x,b.x,acc[0][0]); acc[0][1]=fmaf(a0.x,b.y,acc[0][1]); acc[0][2]=fmaf(a0.x,b.z,acc[0][2]); acc[0][3]=fmaf(a0.x,b.w,acc[0][3]);
            acc[1][0]=fmaf(a0.y,b.x,acc[1][0]); acc[1][1]=fmaf(a0.y,b.y,acc[1][1]); acc[1][2]=fmaf(a0.y,b.z,acc[1][2]); acc[1][3]=fmaf(a0.y,b.w,acc[1][3]);
            acc[2][0]=fmaf(a0.z,b.x,acc[2][0]); acc[2][1]=fmaf(a0.z,b.y,acc[2][1]); acc[2][2]=fmaf(a0.z,b.z,acc[2][2]); acc[2][3]=fmaf(a0.z,b.w,acc[2][3]);
            acc[3][0]=fmaf(a0.w,b.x,acc[3][0]); acc[3][1]=fmaf(a0.w,b.y,acc[3][1]); acc[3][2]=fmaf(a0.w,b.z,acc[3][2]); acc[3][3]=fmaf(a0.w,b.w,acc[3][3]);
            acc[4][0]=fmaf(a1.x,b.x,acc[4][0]); acc[4][1]=fmaf(a1.x,b.y,acc[4][1]); acc[4][2]=fmaf(a1.x,b.z,acc[4][2]); acc[4][3]=fmaf(a1.x,b.w,acc[4][3]);
            acc[5][0]=fmaf(a1.y,b.x,acc[5][0]); acc[5][1]=fmaf(a1.y,b.y,acc[5][1]); acc[5][2]=fmaf(a1.y,b.z,acc[5][2]); acc[5][3]=fmaf(a1.y,b.w,acc[5][3]);
            acc[6][0]=fmaf(a1.z,b.x,acc[6][0]); acc[6][1]=fmaf(a1.z,b.y,acc[6][1]); acc[6][2]=fmaf(a1.z,b.z,acc[6][2]); acc[6][3]=fmaf(a1.z,b.w,acc[6][3]);
            acc[7][0]=fmaf(a1.w,b.x,acc[7][0]); acc[7][1]=fmaf(a1.w,b.y,acc[7][1]); acc[7][2]=fmaf(a1.w,b.z,acc[7][2]); acc[7][3]=fmaf(a1.w,b.w,acc[7][3]);
        }
        __syncthreads();
    }
    #pragma unroll
    for (int i = 0; i < 8; ++i) {
        float4 v = make_float4(acc[i][0], acc[i][1], acc[i][2], acc[i][3]);
        int off = (m0 + (ty << 3) + i) * NC + (tx << 2);
        *(float4*)(outProb + off) = v;
        *(float4*)(outProj + off) = v;
    }
}

// ---------------------------------------------------------------- softmax: probs = softmax(prob)
__global__ __launch_bounds__(256) void k_softmax(const float* __restrict__ prob,
                                                 float* __restrict__ probs) {
    int tid = threadIdx.x;
    int rowLocal = tid >> 4;        // 16 rows per block, 16 lanes per row
    int c4 = (tid & 15) << 2;
    int row = blockIdx.x * 16 + rowLocal;
    float4 v = *(const float4*)(prob + row * NC + c4);
    float mx = fmaxf(fmaxf(v.x, v.y), fmaxf(v.z, v.w));
    for (int off = 1; off < 16; off <<= 1) mx = fmaxf(mx, __shfl_xor(mx, off, 16));
    float e0 = expf(v.x - mx), e1 = expf(v.y - mx), e2 = expf(v.z - mx), e3 = expf(v.w - mx);
    float s = e0 + e1 + e2 + e3;
    for (int off = 1; off < 16; off <<= 1) s += __shfl_xor(s, off, 16);
    float inv = 1.0f / s;
    *(float4*)(probs + row * NC + c4) = make_float4(e0 * inv, e1 * inv, e2 * inv, e3 * inv);
}

// ---------------------------------------------------------------- launch
extern "C" void kernel_launch(void* const* d_in, const int* in_sizes, int n_in,
                              void* d_out, int out_size, void* d_ws, size_t ws_size,
                              hipStream_t stream) {
    const float* X    = (const float*)d_in[0];
    const float* Araw = (const float*)d_in[1];
    const float* Dv   = (const float*)d_in[2];
    const float* Lraw = (const float*)d_in[3];
    float* out = (float*)d_out;
    float* o0 = out;                 // probs  (4194304 floats)
    float* o1 = out + 4194304;       // prob
    float* o2 = out + 8388608;       // P      (1048576 floats)
    float* o3 = out + 9437184;       // proj

    // scratch carved out of output regions (written only by the final kernels):
    float* bufA  = o1;               // A, later squaring pong buffer
    float* bufM  = o1 + 1048576;     // scaled M
    float* bufT  = o1 + 2097152;     // Horner ping
    float* bufP  = o2;               // Horner pong / final P
    float* PL    = o0;               // 65536
    float* Lsig  = o0 + 65536;       // 65536
    float* colp  = o0 + 131072;      // 8*1024
    int*   sInt  = (int*)(o0 + 139264);
    float* plp   = o0 + 262144;      // 8*65536
    float* partG = o0 + 1048576;     // 2*1048576

    k_buildA<<<1024, 256, 0, stream>>>(Araw, Dv, bufA);
    k_colsum<<<32, 256, 0, stream>>>(bufA, colp);
    k_snorm<<<1, 1024, 0, stream>>>(colp, sInt);
    k_scaleM<<<1024, 256, 0, stream>>>(bufA, bufM, sInt);
    k_axpyI<<<1024, 256, 0, stream>>>(bufM, bufT, 1.0f / 8.0f);

    // Horner: T = I + M*T/k, k = 7..1  (degree-8 Taylor of exp(M))
    float* src = bufT;
    float* dst = bufP;
    for (int k = 7; k >= 1; --k) {
        k_gemm_part<<<512, 256, 0, stream>>>(bufM, src, partG, -1, sInt);
        k_combine<<<1024, 256, 0, stream>>>(partG, src, dst, 1.0f / (float)k, 1, -1, sInt);
        float* t = src; src = dst; dst = t;
    }
    // after 7 steps result sits in bufP (src == bufP, dst == bufT)

    // squaring chain: SMAX fixed slots, slot i copies when i >= s
    for (int i = 0; i < SMAX; ++i) {
        k_gemm_part<<<512, 256, 0, stream>>>(src, src, partG, i, sInt);
        k_combine<<<1024, 256, 0, stream>>>(partG, src, dst, 1.0f, 0, i, sInt);
        float* t = src; src = dst; dst = t;
    }
    // SMAX even -> final P in bufP == o2

    k_sigmoid<<<256, 256, 0, stream>>>(Lraw, Lsig);
    k_pl_part<<<128, 256, 0, stream>>>(bufP, Lsig, plp);
    k_pl_comb<<<64, 256, 0, stream>>>(plp, PL);
    k_proj<<<512, 256, 0, stream>>>(X, PL, o1, o3);
    k_softmax<<<4096, 256, 0, stream>>>(o1, o0);
    (void)d_ws; (void)ws_size; (void)in_sizes; (void)n_in; (void)out_size;
}